// Round 12
// baseline (5612.272 us; speedup 1.0000x reference)
//
#include <hip/hip_runtime.h>
#include <hip/hip_bf16.h>
#include <cmath>

#define NN 2048
#define TT 256
#define DD 16
#define HH 256

typedef __attribute__((ext_vector_type(8))) short short8;
typedef __attribute__((ext_vector_type(4))) float f32x4;

__device__ __forceinline__ float sigmoidf_(float x){ return 1.0f/(1.0f+expf(-x)); }

// async 16B/lane global->LDS (LDS dest wave-uniform base; HW adds lane*16)
__device__ __forceinline__ void glds16(const __hip_bfloat16* g, __hip_bfloat16* l){
  __builtin_amdgcn_global_load_lds(
      (const __attribute__((address_space(1))) void*)g,
      (__attribute__((address_space(3))) void*)l, 16, 0, 0);
}

// ---------------- packing ----------------
// W (1024x256) -> P (1024x512): [hi | lo]
__global__ __launch_bounds__(256) void pack_w2(const float* __restrict__ W,
                                               __hip_bfloat16* __restrict__ P){
  int tid = blockIdx.x*256 + threadIdx.x;   // 1024 blocks
  int r = tid >> 8, k = tid & 255;
  float w = W[tid];
  __hip_bfloat16 h = __float2bfloat16(w);
  __hip_bfloat16 l = __float2bfloat16(w - __bfloat162float(h));
  size_t base = (size_t)r*512;
  P[base + k] = h; P[base + 256 + k] = l;
}
// Wih0 (1024 x 16) -> (1024 x 64): [hi | hi | lo | 0] (pairs with x [hi|lo|hi|0])
__global__ __launch_bounds__(256) void pack_w0(const float* __restrict__ W,
                                               __hip_bfloat16* __restrict__ P){
  int tid = blockIdx.x*256 + threadIdx.x;   // 64 blocks
  int r = tid >> 4, k = tid & 15;
  float w = W[tid];
  __hip_bfloat16 h = __float2bfloat16(w);
  __hip_bfloat16 l = __float2bfloat16(w - __bfloat162float(h));
  size_t base = (size_t)r*64;
  P[base + k] = h; P[base + 16 + k] = h; P[base + 32 + k] = l;
  P[base + 48 + k] = __float2bfloat16(0.0f);
}
// x (N,T,16) -> Xp (N,T,64): [hi | lo | hi | 0]
__global__ __launch_bounds__(256) void pack_x(const float* __restrict__ x,
                                              __hip_bfloat16* __restrict__ Xp){
  int tid = blockIdx.x*256 + threadIdx.x;   // 2048 blocks
  const float* xr = x + (size_t)tid*16;
  __hip_bfloat16* o = Xp + (size_t)tid*64;
  for (int k=0;k<16;k++){
    float v = xr[k];
    __hip_bfloat16 h = __float2bfloat16(v);
    __hip_bfloat16 l = __float2bfloat16(v - __bfloat162float(h));
    o[k] = h; o[16+k] = l; o[32+k] = h; o[48+k] = __float2bfloat16(0.0f);
  }
}
__global__ __launch_bounds__(256) void recon_nf(const __hip_bfloat16* __restrict__ hi,
    const __hip_bfloat16* __restrict__ lo, float* __restrict__ nf){
  int tid = blockIdx.x*256 + threadIdx.x;
  nf[tid] = __bfloat162float(hi[tid]) + __bfloat162float(lo[tid]);
}

// ---------------- GEMM segment: merged-A chunks, drain pattern ----------------
// Block tile: 128 m x 16 j x 4 gates. 4 waves; wave stages its 32 m-rows of
// A-hi AND A-lo plus gate-group wv's 16 rows of B-hi and B-lo per k64 chunk.
// Per chunk: stage(12 glds16) -> sync (drains) -> 3-pass MFMA (hi*Bhi, lo*Bhi,
// hi*Blo) -> sync. No load outstanding across a barrier->MFMA boundary.
__device__ __forceinline__ void mm_merged(
    const __hip_bfloat16* __restrict__ Ahi, const __hip_bfloat16* __restrict__ Alo,
    size_t lda,
    const __hip_bfloat16* __restrict__ Bhi, const __hip_bfloat16* __restrict__ Blo,
    size_t ldb, int Klen,
    int m0, int j0, int wv, int lane, int rr, int sw8, int frow,
    f32x4 (&acc)[2][4],
    __hip_bfloat16* AsH, __hip_bfloat16* AsL,
    __hip_bfloat16* BsH, __hip_bfloat16* BsL)
{
  const size_t arow = (size_t)(m0 + wv*32 + rr)*lda + sw8;
  const size_t brow = (size_t)(wv*256 + j0 + rr)*ldb + sw8;
  for (int kb=0; kb<Klen; kb+=64){
    {
      const __hip_bfloat16* AbH = Ahi + arow + kb;
      __hip_bfloat16* AdH = AsH + (wv*32)*64;
      #pragma unroll
      for (int c2=0;c2<4;c2++) glds16(AbH + (size_t)(c2*8)*lda, AdH + c2*8*64);
      const __hip_bfloat16* AbL = Alo + arow + kb;
      __hip_bfloat16* AdL = AsL + (wv*32)*64;
      #pragma unroll
      for (int c2=0;c2<4;c2++) glds16(AbL + (size_t)(c2*8)*lda, AdL + c2*8*64);
      const __hip_bfloat16* Bb1 = Bhi + brow + kb;
      __hip_bfloat16* Bd1 = BsH + (wv<<4)*64;
      glds16(Bb1, Bd1); glds16(Bb1 + (size_t)8*ldb, Bd1 + 8*64);
      const __hip_bfloat16* Bb2 = Blo + brow + kb;
      __hip_bfloat16* Bd2 = BsL + (wv<<4)*64;
      glds16(Bb2, Bd2); glds16(Bb2 + (size_t)8*ldb, Bd2 + 8*64);
    }
    __syncthreads();          // drains this chunk's loads
    #pragma unroll
    for (int w2=0; w2<2; ++w2){
      const int sl8 = ((((w2<<2) + (lane>>4)) ^ (lane&7)) << 3);
      short8 ah0 = *(const short8*)&AsH[(wv*32 +      frow)*64 + sl8];
      short8 ah1 = *(const short8*)&AsH[(wv*32 + 16 + frow)*64 + sl8];
      short8 al0 = *(const short8*)&AsL[(wv*32 +      frow)*64 + sl8];
      short8 al1 = *(const short8*)&AsL[(wv*32 + 16 + frow)*64 + sl8];
      #pragma unroll
      for (int g=0; g<4; ++g){
        short8 bh = *(const short8*)&BsH[((g<<4) + frow)*64 + sl8];
        acc[0][g] = __builtin_amdgcn_mfma_f32_16x16x32_bf16(ah0, bh, acc[0][g], 0,0,0);
        acc[1][g] = __builtin_amdgcn_mfma_f32_16x16x32_bf16(ah1, bh, acc[1][g], 0,0,0);
        acc[0][g] = __builtin_amdgcn_mfma_f32_16x16x32_bf16(al0, bh, acc[0][g], 0,0,0);
        acc[1][g] = __builtin_amdgcn_mfma_f32_16x16x32_bf16(al1, bh, acc[1][g], 0,0,0);
        short8 bl = *(const short8*)&BsL[((g<<4) + frow)*64 + sl8];
        acc[0][g] = __builtin_amdgcn_mfma_f32_16x16x32_bf16(ah0, bl, acc[0][g], 0,0,0);
        acc[1][g] = __builtin_amdgcn_mfma_f32_16x16x32_bf16(ah1, bl, acc[1][g], 0,0,0);
      }
    }
    __syncthreads();
  }
}

// single-B, one 64-panel (for the K=64 x-chunk) — exact R8 shape
__device__ __forceinline__ void mm_single64(
    const __hip_bfloat16* __restrict__ A, size_t lda,
    const __hip_bfloat16* __restrict__ B, size_t ldb,
    int m0, int j0, int wv, int lane, int rr, int sw8, int frow,
    f32x4 (&acc)[2][4],
    __hip_bfloat16* As0, __hip_bfloat16* Bh0)
{
  {
    const __hip_bfloat16* Ab = A + (size_t)(m0 + wv*32 + rr)*lda + sw8;
    __hip_bfloat16* Ad = As0 + (wv*32)*64;
    #pragma unroll
    for (int c2=0;c2<4;c2++) glds16(Ab + (size_t)(c2*8)*lda, Ad + c2*8*64);
    const __hip_bfloat16* Bb1 = B + (size_t)(wv*256 + j0 + rr)*ldb + sw8;
    __hip_bfloat16* Bd1 = Bh0 + (wv<<4)*64;
    glds16(Bb1, Bd1); glds16(Bb1 + (size_t)8*ldb, Bd1 + 8*64);
  }
  __syncthreads();
  #pragma unroll
  for (int w2=0; w2<2; ++w2){
    const int sl8 = ((((w2<<2) + (lane>>4)) ^ (lane&7)) << 3);
    short8 a0 = *(const short8*)&As0[(wv*32 +      frow)*64 + sl8];
    short8 a1 = *(const short8*)&As0[(wv*32 + 16 + frow)*64 + sl8];
    #pragma unroll
    for (int g=0; g<4; ++g){
      short8 b1 = *(const short8*)&Bh0[((g<<4) + frow)*64 + sl8];
      acc[0][g] = __builtin_amdgcn_mfma_f32_16x16x32_bf16(a0, b1, acc[0][g], 0,0,0);
      acc[1][g] = __builtin_amdgcn_mfma_f32_16x16x32_bf16(a1, b1, acc[1][g], 0,0,0);
    }
  }
  __syncthreads();
}

// ---------------- fused two-layer skewed LSTM step (MFMA bf16x3) ----------------
// Launch t: blocks [0,256) layer0 step t; [256,512) layer1 step t-1.
// LDS 48 KB -> up to 3 blocks/CU for cross-block drain/MFMA overlap.
__global__ __launch_bounds__(256, 3) void lstm2_step(
    int t,
    const __hip_bfloat16* __restrict__ Xp,
    const __hip_bfloat16* __restrict__ P0ih,
    const __hip_bfloat16* __restrict__ P0hh,
    const __hip_bfloat16* __restrict__ P1ih,
    const __hip_bfloat16* __restrict__ P1hh,
    const float* __restrict__ bih0, const float* __restrict__ bhh0,
    const float* __restrict__ bih1, const float* __restrict__ bhh1,
    const __hip_bfloat16* __restrict__ h0p_hi, const __hip_bfloat16* __restrict__ h0p_lo,
    __hip_bfloat16* __restrict__ h0o_hi, __hip_bfloat16* __restrict__ h0o_lo,
    const __hip_bfloat16* __restrict__ h1p_hi, const __hip_bfloat16* __restrict__ h1p_lo,
    __hip_bfloat16* __restrict__ h1o_hi, __hip_bfloat16* __restrict__ h1o_lo,
    float* __restrict__ c0, float* __restrict__ c1)
{
  __shared__ __align__(16) __hip_bfloat16 AsH[128*64];   // 16 KB
  __shared__ __align__(16) __hip_bfloat16 AsL[128*64];   // 16 KB
  __shared__ __align__(16) __hip_bfloat16 BsH[64*64];    // 8 KB
  __shared__ __align__(16) __hip_bfloat16 BsL[64*64];    // 8 KB

  const int bid = blockIdx.x;
  const bool isL0 = bid < 256;
  if (isL0 && t >= TT) return;
  if (!isL0 && t == 0) return;
  const int idx = bid & 255;
  const int m0 = (idx >> 4) << 7;
  const int j0 = (idx & 15) << 4;
  const int lane = threadIdx.x & 63, wv = threadIdx.x >> 6;
  const int rr = lane >> 3;
  const int sw8 = (((lane & 7) ^ rr) << 3);     // source-side XOR swizzle
  const int frow = lane & 15;

  f32x4 acc[2][4] = {};                 // [m-subtile][gate]

  if (isL0){
    if (t != 0){
      mm_merged(h0p_hi, h0p_lo, 256, P0hh, P0hh+256, 512, 256,
                m0, j0, wv, lane, rr, sw8, frow, acc, AsH, AsL, BsH, BsL);
    }
    mm_single64(Xp + (size_t)t*64, (size_t)TT*64, P0ih, 64,
                m0, j0, wv, lane, rr, sw8, frow, acc, AsH, BsH);
  } else {
    mm_merged(h0p_hi, h0p_lo, 256, P1ih, P1ih+256, 512, 256,
              m0, j0, wv, lane, rr, sw8, frow, acc, AsH, AsL, BsH, BsL);
    if (t != 1){
      mm_merged(h1p_hi, h1p_lo, 256, P1hh, P1hh+256, 512, 256,
                m0, j0, wv, lane, rr, sw8, frow, acc, AsH, AsL, BsH, BsL);
    }
  }

  // epilogue: lane holds all 4 gates. C map: col=lane&15, row=(lane>>4)*4+r
  const int j = j0 + frow;
  const float* bih = isL0 ? bih0 : bih1;
  const float* bhh = isL0 ? bhh0 : bhh1;
  float* cst = isL0 ? c0 : c1;
  __hip_bfloat16* ohi = isL0 ? h0o_hi : h1o_hi;
  __hip_bfloat16* olo = isL0 ? h0o_lo : h1o_lo;
  const int first = isL0 ? (t==0) : (t==1);
  const float b0 = bih[j]        + bhh[j];
  const float b1 = bih[HH + j]   + bhh[HH + j];
  const float b2 = bih[2*HH + j] + bhh[2*HH + j];
  const float b3 = bih[3*HH + j] + bhh[3*HH + j];
  #pragma unroll
  for (int mt=0; mt<2; ++mt){
    const int mrb = m0 + wv*32 + mt*16 + ((lane>>4)<<2);
    #pragma unroll
    for (int r=0; r<4; ++r){
      const size_t mi = (size_t)(mrb + r)*HH + j;
      float gi = acc[mt][0][r] + b0;
      float gf = acc[mt][1][r] + b1;
      float gg = acc[mt][2][r] + b2;
      float go = acc[mt][3][r] + b3;
      float cold = first ? 0.f : cst[mi];
      float cn = sigmoidf_(gf)*cold + sigmoidf_(gi)*tanhf(gg);
      float hv = sigmoidf_(go)*tanhf(cn);
      cst[mi] = cn;
      __hip_bfloat16 hb = __float2bfloat16(hv);
      ohi[mi] = hb;
      olo[mi] = __float2bfloat16(hv - __bfloat162float(hb));
    }
  }
}

// ---------------- fp32 tail (unchanged, proven) ----------------
__global__ __launch_bounds__(256) void gemm_nn(
    float* __restrict__ C, const float* __restrict__ A, const float* __restrict__ B,
    int K, int lda, int ldb, int ldc, int relu)
{
  __shared__ float As_[16][68];
  __shared__ float Bs_[16][64];
  float acc[4][4] = {};
  const int tx = threadIdx.x;
  const int m0 = blockIdx.y<<6, n0 = blockIdx.x<<6;
  const int am = tx>>2, ak = (tx&3)<<2;
  const int bk = tx>>4, bn = (tx&15)<<2;
  const int mm = (tx>>4)<<2, nc = (tx&15)<<2;
  for (int kb=0; kb<K; kb+=16){
    float4 av = *reinterpret_cast<const float4*>(A + (size_t)(m0+am)*lda + kb + ak);
    As_[ak][am]=av.x; As_[ak+1][am]=av.y; As_[ak+2][am]=av.z; As_[ak+3][am]=av.w;
    *reinterpret_cast<float4*>(&Bs_[bk][bn]) =
      *reinterpret_cast<const float4*>(B + (size_t)(kb+bk)*ldb + n0 + bn);
    __syncthreads();
    #pragma unroll
    for (int k=0;k<16;k++){
      float4 a4 = *reinterpret_cast<const float4*>(&As_[k][mm]);
      float4 b4 = *reinterpret_cast<const float4*>(&Bs_[k][nc]);
      acc[0][0]=fmaf(a4.x,b4.x,acc[0][0]); acc[0][1]=fmaf(a4.x,b4.y,acc[0][1]);
      acc[0][2]=fmaf(a4.x,b4.z,acc[0][2]); acc[0][3]=fmaf(a4.x,b4.w,acc[0][3]);
      acc[1][0]=fmaf(a4.y,b4.x,acc[1][0]); acc[1][1]=fmaf(a4.y,b4.y,acc[1][1]);
      acc[1][2]=fmaf(a4.y,b4.z,acc[1][2]); acc[1][3]=fmaf(a4.y,b4.w,acc[1][3]);
      acc[2][0]=fmaf(a4.z,b4.x,acc[2][0]); acc[2][1]=fmaf(a4.z,b4.y,acc[2][1]);
      acc[2][2]=fmaf(a4.z,b4.z,acc[2][2]); acc[2][3]=fmaf(a4.z,b4.w,acc[2][3]);
      acc[3][0]=fmaf(a4.w,b4.x,acc[3][0]); acc[3][1]=fmaf(a4.w,b4.y,acc[3][1]);
      acc[3][2]=fmaf(a4.w,b4.z,acc[3][2]); acc[3][3]=fmaf(a4.w,b4.w,acc[3][3]);
    }
    __syncthreads();
  }
  #pragma unroll
  for (int r=0;r<4;r++){
    float4 v = make_float4(acc[r][0],acc[r][1],acc[r][2],acc[r][3]);
    if (relu){ v.x=fmaxf(v.x,0.f); v.y=fmaxf(v.y,0.f); v.z=fmaxf(v.z,0.f); v.w=fmaxf(v.w,0.f); }
    *reinterpret_cast<float4*>(C + (size_t)(m0+mm+r)*ldc + n0 + nc) = v;
  }
}

__global__ __launch_bounds__(256) void gemm_nt(
    float* __restrict__ C, const float* __restrict__ A, const float* __restrict__ B,
    int K, int lda, int ldb, int ldc)
{
  __shared__ float As_[16][68];
  __shared__ float Bs_[16][68];
  float acc[4][4] = {};
  const int tx = threadIdx.x;
  const int m0 = blockIdx.y<<6, n0 = blockIdx.x<<6;
  const int am = tx>>2, ak = (tx&3)<<2;
  const int mm = (tx>>4)<<2, nc = (tx&15)<<2;
  for (int kb=0; kb<K; kb+=16){
    float4 av = *reinterpret_cast<const float4*>(A + (size_t)(m0+am)*lda + kb + ak);
    As_[ak][am]=av.x; As_[ak+1][am]=av.y; As_[ak+2][am]=av.z; As_[ak+3][am]=av.w;
    float4 bv = *reinterpret_cast<const float4*>(B + (size_t)(n0+am)*ldb + kb + ak);
    Bs_[ak][am]=bv.x; Bs_[ak+1][am]=bv.y; Bs_[ak+2][am]=bv.z; Bs_[ak+3][am]=bv.w;
    __syncthreads();
    #pragma unroll
    for (int k=0;k<16;k++){
      float4 a4 = *reinterpret_cast<const float4*>(&As_[k][mm]);
      float4 b4 = *reinterpret_cast<const float4*>(&Bs_[k][nc]);
      acc[0][0]=fmaf(a4.x,b4.x,acc[0][0]); acc[0][1]=fmaf(a4.x,b4.y,acc[0][1]);
      acc[0][2]=fmaf(a4.x,b4.z,acc[0][2]); acc[0][3]=fmaf(a4.x,b4.w,acc[0][3]);
      acc[1][0]=fmaf(a4.y,b4.x,acc[1][0]); acc[1][1]=fmaf(a4.y,b4.y,acc[1][1]);
      acc[1][2]=fmaf(a4.y,b4.z,acc[1][2]); acc[1][3]=fmaf(a4.y,b4.w,acc[1][3]);
      acc[2][0]=fmaf(a4.z,b4.x,acc[2][0]); acc[2][1]=fmaf(a4.z,b4.y,acc[2][1]);
      acc[2][2]=fmaf(a4.z,b4.z,acc[2][2]); acc[2][3]=fmaf(a4.z,b4.w,acc[2][3]);
      acc[3][0]=fmaf(a4.w,b4.x,acc[3][0]); acc[3][1]=fmaf(a4.w,b4.y,acc[3][1]);
      acc[3][2]=fmaf(a4.w,b4.z,acc[3][2]); acc[3][3]=fmaf(a4.w,b4.w,acc[3][3]);
    }
    __syncthreads();
  }
  #pragma unroll
  for (int r=0;r<4;r++){
    float4 v = make_float4(acc[r][0],acc[r][1],acc[r][2],acc[r][3]);
    *reinterpret_cast<float4*>(C + (size_t)(m0+mm+r)*ldc + n0 + nc) = v;
  }
}

__global__ __launch_bounds__(256) void rowstat(const float* __restrict__ nf,
    float* __restrict__ xc, float* __restrict__ dvec)
{
  __shared__ float red[256];
  int n = blockIdx.x, tx = threadIdx.x;
  float v = nf[(size_t)n*HH + tx];
  red[tx] = v; __syncthreads();
  for (int s=128; s>0; s>>=1){ if (tx<s) red[tx]+=red[tx+s]; __syncthreads(); }
  float mean = red[0] * (1.0f/HH);
  __syncthreads();
  float d = v - mean;
  xc[(size_t)n*HH + tx] = d;
  red[tx] = d*d; __syncthreads();
  for (int s=128; s>0; s>>=1){ if (tx<s) red[tx]+=red[tx+s]; __syncthreads(); }
  if (tx==0) dvec[n] = sqrtf(red[0]);
}

__global__ __launch_bounds__(256) void rowsum(const float* __restrict__ cov,
    const float* __restrict__ dvec, float* __restrict__ dinv)
{
  __shared__ float red[256];
  int i = blockIdx.x, tx = threadIdx.x;
  float di = dvec[i];
  float s = 0.f;
  for (int jj=tx; jj<NN; jj+=256){
    float r = cov[(size_t)i*NN + jj] / (di * dvec[jj]);
    if (r != r) r = 0.f; else r = fminf(1.f, fmaxf(-1.f, r));
    s += r;
  }
  red[tx]=s; __syncthreads();
  for (int st=128; st>0; st>>=1){ if (tx<st) red[tx]+=red[tx+st]; __syncthreads(); }
  if (tx==0){
    float tot = red[0] + 1.0f;
    float p = powf(tot, -0.5f);
    if (isinf(p)) p = 0.f;
    dinv[i] = p;
  }
}

__global__ __launch_bounds__(256) void adjnorm(float* __restrict__ cov,
    const float* __restrict__ dvec, const float* __restrict__ dinv)
{
  size_t idx = (size_t)blockIdx.x*256 + threadIdx.x;
  int i = (int)(idx >> 11), jj = (int)(idx & (NN-1));
  float r = cov[idx] / (dvec[i]*dvec[jj]);
  if (r != r) r = 0.f; else r = fminf(1.f, fmaxf(-1.f, r));
  if (i==jj) r += 1.f;
  cov[idx] = dinv[i]*r*dinv[jj];
}

__global__ __launch_bounds__(128) void predk(const float* __restrict__ G2,
    const float* __restrict__ Wfc, const float* __restrict__ bfc, float* __restrict__ out)
{
  int n = blockIdx.x, tx = threadIdx.x;
  float v = G2[(size_t)n*128 + tx] * Wfc[tx];
  for (int off=32; off>0; off>>=1) v += __shfl_down(v, off);
  __shared__ float p[2];
  if ((tx&63)==0) p[tx>>6] = v;
  __syncthreads();
  if (tx==0) out[n] = p[0] + p[1] + bfc[0];
}

extern "C" void kernel_launch(void* const* d_in, const int* in_sizes, int n_in,
                              void* d_out, int out_size, void* d_ws, size_t ws_size,
                              hipStream_t stream)
{
  const float* x    = (const float*)d_in[0];
  const float* Wih0 = (const float*)d_in[1];
  const float* Whh0 = (const float*)d_in[2];
  const float* bih0 = (const float*)d_in[3];
  const float* bhh0 = (const float*)d_in[4];
  const float* Wih1 = (const float*)d_in[5];
  const float* Whh1 = (const float*)d_in[6];
  const float* bih1 = (const float*)d_in[7];
  const float* bhh1 = (const float*)d_in[8];
  const float* Wg1  = (const float*)d_in[9];
  const float* Wg2  = (const float*)d_in[10];
  const float* Wfc  = (const float*)d_in[11];
  const float* bfc  = (const float*)d_in[12];
  float* out = (float*)d_out;

  char* w = (char*)d_ws;
  auto alloc = [&](size_t bytes){ char* p = w; w += (bytes + 255) & ~(size_t)255; return p; };
  __hip_bfloat16* Xp   = (__hip_bfloat16*)alloc((size_t)NN*TT*64*2);
  __hip_bfloat16* P0hh = (__hip_bfloat16*)alloc((size_t)1024*512*2);
  __hip_bfloat16* P1ih = (__hip_bfloat16*)alloc((size_t)1024*512*2);
  __hip_bfloat16* P1hh = (__hip_bfloat16*)alloc((size_t)1024*512*2);
  __hip_bfloat16* P0ih = (__hip_bfloat16*)alloc((size_t)1024*64*2);
  __hip_bfloat16 *H0hi[2], *H0lo[2], *H1hi[2], *H1lo[2];
  for (int i=0;i<2;i++){ H0hi[i]=(__hip_bfloat16*)alloc((size_t)NN*HH*2);
                         H0lo[i]=(__hip_bfloat16*)alloc((size_t)NN*HH*2); }
  for (int i=0;i<2;i++){ H1hi[i]=(__hip_bfloat16*)alloc((size_t)NN*HH*2);
                         H1lo[i]=(__hip_bfloat16*)alloc((size_t)NN*HH*2); }
  float* c0   = (float*)alloc((size_t)NN*HH*4);
  float* c1   = (float*)alloc((size_t)NN*HH*4);
  float* nf   = (float*)alloc((size_t)NN*HH*4);
  float* xc   = (float*)alloc((size_t)NN*HH*4);
  float* cov  = (float*)alloc((size_t)NN*NN*4);
  float* t1   = (float*)alloc((size_t)NN*HH*4);
  float* G1   = (float*)alloc((size_t)NN*HH*4);
  float* t2   = (float*)alloc((size_t)NN*128*4);
  float* G2   = (float*)alloc((size_t)NN*128*4);
  float* dvec = (float*)alloc((size_t)NN*4);
  float* dinv = (float*)alloc((size_t)NN*4);

  hipLaunchKernelGGL(pack_w2, dim3(1024), dim3(256), 0, stream, Whh0, P0hh);
  hipLaunchKernelGGL(pack_w2, dim3(1024), dim3(256), 0, stream, Wih1, P1ih);
  hipLaunchKernelGGL(pack_w2, dim3(1024), dim3(256), 0, stream, Whh1, P1hh);
  hipLaunchKernelGGL(pack_w0, dim3(64),   dim3(256), 0, stream, Wih0, P0ih);
  hipLaunchKernelGGL(pack_x,  dim3(2048), dim3(256), 0, stream, x, Xp);

  // skewed recurrence: launch t runs L0(t) and L1(t-1)
  for (int t=0; t<=TT; ++t){
    const __hip_bfloat16 *h0p_hi = H0hi[(t+1)&1], *h0p_lo = H0lo[(t+1)&1];
    __hip_bfloat16 *h0o_hi = H0hi[t&1], *h0o_lo = H0lo[t&1];
    const __hip_bfloat16 *h1p_hi = H1hi[t&1], *h1p_lo = H1lo[t&1];
    __hip_bfloat16 *h1o_hi = H1hi[(t+1)&1], *h1o_lo = H1lo[(t+1)&1];
    hipLaunchKernelGGL(lstm2_step, dim3(512), dim3(256), 0, stream,
        t, Xp, P0ih, P0hh, P1ih, P1hh, bih0, bhh0, bih1, bhh1,
        h0p_hi, h0p_lo, h0o_hi, h0o_lo, h1p_hi, h1p_lo, h1o_hi, h1o_lo, c0, c1);
  }
  // final h1 (step 255, written at launch t=256) lives in H1[1]
  hipLaunchKernelGGL(recon_nf, dim3(2048), dim3(256), 0, stream, H1hi[1], H1lo[1], nf);

  hipLaunchKernelGGL(rowstat, dim3(NN), dim3(256), 0, stream, nf, xc, dvec);
  hipLaunchKernelGGL(gemm_nt, dim3(NN/64, NN/64), dim3(256), 0, stream,
      cov, xc, xc, HH, HH, HH, NN);
  hipLaunchKernelGGL(rowsum, dim3(NN), dim3(256), 0, stream, cov, dvec, dinv);
  hipLaunchKernelGGL(adjnorm, dim3(NN*NN/256), dim3(256), 0, stream, cov, dvec, dinv);

  hipLaunchKernelGGL(gemm_nn, dim3(HH/64, NN/64), dim3(256), 0, stream,
      t1, nf, Wg1, HH, HH, HH, HH, 0);
  hipLaunchKernelGGL(gemm_nn, dim3(HH/64, NN/64), dim3(256), 0, stream,
      G1, cov, t1, NN, NN, HH, HH, 1);
  hipLaunchKernelGGL(gemm_nn, dim3(128/64, NN/64), dim3(256), 0, stream,
      t2, G1, Wg2, HH, HH, 128, 128, 0);
  hipLaunchKernelGGL(gemm_nn, dim3(128/64, NN/64), dim3(256), 0, stream,
      G2, cov, t2, NN, NN, 128, 128, 0);
  hipLaunchKernelGGL(predk, dim3(NN), dim3(128), 0, stream, G2, Wfc, bfc, out);
}

// Round 13
// 4881.313 us; speedup vs baseline: 1.1497x; 1.1497x over previous
//
#include <hip/hip_runtime.h>
#include <hip/hip_bf16.h>
#include <cmath>

#define NN 2048
#define TT 256
#define DD 16
#define HH 256

typedef __attribute__((ext_vector_type(8))) short short8;
typedef __attribute__((ext_vector_type(4))) float f32x4;

__device__ __forceinline__ float sigmoidf_(float x){ return 1.0f/(1.0f+expf(-x)); }

// async 16B/lane global->LDS (LDS dest wave-uniform base; HW adds lane*16)
__device__ __forceinline__ void glds16(const __hip_bfloat16* g, __hip_bfloat16* l){
  __builtin_amdgcn_global_load_lds(
      (const __attribute__((address_space(1))) void*)g,
      (__attribute__((address_space(3))) void*)l, 16, 0, 0);
}

// ---------------- packing ----------------
// W (1024x256) -> P (1024x512): [hi | lo]
__global__ __launch_bounds__(256) void pack_w2(const float* __restrict__ W,
                                               __hip_bfloat16* __restrict__ P){
  int tid = blockIdx.x*256 + threadIdx.x;   // 1024 blocks
  int r = tid >> 8, k = tid & 255;
  float w = W[tid];
  __hip_bfloat16 h = __float2bfloat16(w);
  __hip_bfloat16 l = __float2bfloat16(w - __bfloat162float(h));
  size_t base = (size_t)r*512;
  P[base + k] = h; P[base + 256 + k] = l;
}
// Wih0 (1024 x 16) -> (1024 x 64): [hi | hi | lo | 0] (pairs with x [hi|lo|hi|0])
__global__ __launch_bounds__(256) void pack_w0(const float* __restrict__ W,
                                               __hip_bfloat16* __restrict__ P){
  int tid = blockIdx.x*256 + threadIdx.x;   // 64 blocks
  int r = tid >> 4, k = tid & 15;
  float w = W[tid];
  __hip_bfloat16 h = __float2bfloat16(w);
  __hip_bfloat16 l = __float2bfloat16(w - __bfloat162float(h));
  size_t base = (size_t)r*64;
  P[base + k] = h; P[base + 16 + k] = h; P[base + 32 + k] = l;
  P[base + 48 + k] = __float2bfloat16(0.0f);
}
// x (N,T,16) -> Xp (N,T,64): [hi | lo | hi | 0]
__global__ __launch_bounds__(256) void pack_x(const float* __restrict__ x,
                                              __hip_bfloat16* __restrict__ Xp){
  int tid = blockIdx.x*256 + threadIdx.x;   // 2048 blocks
  const float* xr = x + (size_t)tid*16;
  __hip_bfloat16* o = Xp + (size_t)tid*64;
  for (int k=0;k<16;k++){
    float v = xr[k];
    __hip_bfloat16 h = __float2bfloat16(v);
    __hip_bfloat16 l = __float2bfloat16(v - __bfloat162float(h));
    o[k] = h; o[16+k] = l; o[32+k] = h; o[48+k] = __float2bfloat16(0.0f);
  }
}
__global__ __launch_bounds__(256) void recon_nf(const __hip_bfloat16* __restrict__ hi,
    const __hip_bfloat16* __restrict__ lo, float* __restrict__ nf){
  int tid = blockIdx.x*256 + threadIdx.x;
  nf[tid] = __bfloat162float(hi[tid]) + __bfloat162float(lo[tid]);
}

// ---------------- GEMM segment: merged-A chunks, drain pattern ----------------
// Block tile: 128 m x 16 j x 4 gates. 4 waves; wave stages its 32 m-rows of
// A-hi AND A-lo plus gate-group wv's 16 rows of B-hi and B-lo per k64 chunk.
// Per chunk: stage(12 glds16) -> sync (drains) -> 3-pass MFMA (hi*Bhi, lo*Bhi,
// hi*Blo) -> sync. No load outstanding across a barrier->MFMA boundary.
__device__ __forceinline__ void mm_merged(
    const __hip_bfloat16* __restrict__ Ahi, const __hip_bfloat16* __restrict__ Alo,
    size_t lda,
    const __hip_bfloat16* __restrict__ Bhi, const __hip_bfloat16* __restrict__ Blo,
    size_t ldb, int Klen,
    int m0, int j0, int wv, int lane, int rr, int sw8, int frow,
    f32x4 (&acc)[2][4],
    __hip_bfloat16* AsH, __hip_bfloat16* AsL,
    __hip_bfloat16* BsH, __hip_bfloat16* BsL)
{
  const size_t arow = (size_t)(m0 + wv*32 + rr)*lda + sw8;
  const size_t brow = (size_t)(wv*256 + j0 + rr)*ldb + sw8;
  for (int kb=0; kb<Klen; kb+=64){
    {
      const __hip_bfloat16* AbH = Ahi + arow + kb;
      __hip_bfloat16* AdH = AsH + (wv*32)*64;
      #pragma unroll
      for (int c2=0;c2<4;c2++) glds16(AbH + (size_t)(c2*8)*lda, AdH + c2*8*64);
      const __hip_bfloat16* AbL = Alo + arow + kb;
      __hip_bfloat16* AdL = AsL + (wv*32)*64;
      #pragma unroll
      for (int c2=0;c2<4;c2++) glds16(AbL + (size_t)(c2*8)*lda, AdL + c2*8*64);
      const __hip_bfloat16* Bb1 = Bhi + brow + kb;
      __hip_bfloat16* Bd1 = BsH + (wv<<4)*64;
      glds16(Bb1, Bd1); glds16(Bb1 + (size_t)8*ldb, Bd1 + 8*64);
      const __hip_bfloat16* Bb2 = Blo + brow + kb;
      __hip_bfloat16* Bd2 = BsL + (wv<<4)*64;
      glds16(Bb2, Bd2); glds16(Bb2 + (size_t)8*ldb, Bd2 + 8*64);
    }
    __syncthreads();          // drains this chunk's loads
    #pragma unroll
    for (int w2=0; w2<2; ++w2){
      const int sl8 = ((((w2<<2) + (lane>>4)) ^ (lane&7)) << 3);
      short8 ah0 = *(const short8*)&AsH[(wv*32 +      frow)*64 + sl8];
      short8 ah1 = *(const short8*)&AsH[(wv*32 + 16 + frow)*64 + sl8];
      short8 al0 = *(const short8*)&AsL[(wv*32 +      frow)*64 + sl8];
      short8 al1 = *(const short8*)&AsL[(wv*32 + 16 + frow)*64 + sl8];
      #pragma unroll
      for (int g=0; g<4; ++g){
        short8 bh = *(const short8*)&BsH[((g<<4) + frow)*64 + sl8];
        acc[0][g] = __builtin_amdgcn_mfma_f32_16x16x32_bf16(ah0, bh, acc[0][g], 0,0,0);
        acc[1][g] = __builtin_amdgcn_mfma_f32_16x16x32_bf16(ah1, bh, acc[1][g], 0,0,0);
        acc[0][g] = __builtin_amdgcn_mfma_f32_16x16x32_bf16(al0, bh, acc[0][g], 0,0,0);
        acc[1][g] = __builtin_amdgcn_mfma_f32_16x16x32_bf16(al1, bh, acc[1][g], 0,0,0);
        short8 bl = *(const short8*)&BsL[((g<<4) + frow)*64 + sl8];
        acc[0][g] = __builtin_amdgcn_mfma_f32_16x16x32_bf16(ah0, bl, acc[0][g], 0,0,0);
        acc[1][g] = __builtin_amdgcn_mfma_f32_16x16x32_bf16(ah1, bl, acc[1][g], 0,0,0);
      }
    }
    __syncthreads();
  }
}

// single-B, one 64-panel (for the K=64 x-chunk) — exact R8 shape
__device__ __forceinline__ void mm_single64(
    const __hip_bfloat16* __restrict__ A, size_t lda,
    const __hip_bfloat16* __restrict__ B, size_t ldb,
    int m0, int j0, int wv, int lane, int rr, int sw8, int frow,
    f32x4 (&acc)[2][4],
    __hip_bfloat16* As0, __hip_bfloat16* Bh0)
{
  {
    const __hip_bfloat16* Ab = A + (size_t)(m0 + wv*32 + rr)*lda + sw8;
    __hip_bfloat16* Ad = As0 + (wv*32)*64;
    #pragma unroll
    for (int c2=0;c2<4;c2++) glds16(Ab + (size_t)(c2*8)*lda, Ad + c2*8*64);
    const __hip_bfloat16* Bb1 = B + (size_t)(wv*256 + j0 + rr)*ldb + sw8;
    __hip_bfloat16* Bd1 = Bh0 + (wv<<4)*64;
    glds16(Bb1, Bd1); glds16(Bb1 + (size_t)8*ldb, Bd1 + 8*64);
  }
  __syncthreads();
  #pragma unroll
  for (int w2=0; w2<2; ++w2){
    const int sl8 = ((((w2<<2) + (lane>>4)) ^ (lane&7)) << 3);
    short8 a0 = *(const short8*)&As0[(wv*32 +      frow)*64 + sl8];
    short8 a1 = *(const short8*)&As0[(wv*32 + 16 + frow)*64 + sl8];
    #pragma unroll
    for (int g=0; g<4; ++g){
      short8 b1 = *(const short8*)&Bh0[((g<<4) + frow)*64 + sl8];
      acc[0][g] = __builtin_amdgcn_mfma_f32_16x16x32_bf16(a0, b1, acc[0][g], 0,0,0);
      acc[1][g] = __builtin_amdgcn_mfma_f32_16x16x32_bf16(a1, b1, acc[1][g], 0,0,0);
    }
  }
  __syncthreads();
}

// ---------------- fused two-layer skewed LSTM step (MFMA bf16x3) ----------------
// XCD-aware mapping (round-robin bid->XCD assumed, perf-only): XCDs 0-3 run
// layer0, XCDs 4-7 run layer1. Within a layer's 4 XCDs, each XCD owns an
// (8 mg x 8 jg) quadrant so its L2 working set (weight j-slice + h m-slice)
// fits in 4 MB: L0 ~2 MB, L1 ~4 MB. Pure relabeling; per-block math unchanged.
__global__ __launch_bounds__(256, 2) void lstm2_step(
    int t,
    const __hip_bfloat16* __restrict__ Xp,
    const __hip_bfloat16* __restrict__ P0ih,
    const __hip_bfloat16* __restrict__ P0hh,
    const __hip_bfloat16* __restrict__ P1ih,
    const __hip_bfloat16* __restrict__ P1hh,
    const float* __restrict__ bih0, const float* __restrict__ bhh0,
    const float* __restrict__ bih1, const float* __restrict__ bhh1,
    const __hip_bfloat16* __restrict__ h0p_hi, const __hip_bfloat16* __restrict__ h0p_lo,
    __hip_bfloat16* __restrict__ h0o_hi, __hip_bfloat16* __restrict__ h0o_lo,
    const __hip_bfloat16* __restrict__ h1p_hi, const __hip_bfloat16* __restrict__ h1p_lo,
    __hip_bfloat16* __restrict__ h1o_hi, __hip_bfloat16* __restrict__ h1o_lo,
    float* __restrict__ c0, float* __restrict__ c1)
{
  __shared__ __align__(16) __hip_bfloat16 AsH[128*64];   // 16 KB
  __shared__ __align__(16) __hip_bfloat16 AsL[128*64];   // 16 KB
  __shared__ __align__(16) __hip_bfloat16 BsH[64*64];    // 8 KB
  __shared__ __align__(16) __hip_bfloat16 BsL[64*64];    // 8 KB

  const int bid = blockIdx.x;
  const int xcd = bid & 7;            // presumed XCD (round-robin dispatch)
  const int slot = bid >> 3;          // 0..63 within this XCD
  const bool isL0 = xcd < 4;
  if (isL0 && t >= TT) return;
  if (!isL0 && t == 0) return;
  const int lg = isL0 ? xcd : (xcd - 4);          // 2-bit quadrant id
  const int jg = ((lg & 1) << 3) + (slot & 7);    // 0..15
  const int mg = ((lg >> 1) << 3) + (slot >> 3);  // 0..15
  const int m0 = mg << 7;
  const int j0 = jg << 4;
  const int lane = threadIdx.x & 63, wv = threadIdx.x >> 6;
  const int rr = lane >> 3;
  const int sw8 = (((lane & 7) ^ rr) << 3);     // source-side XOR swizzle
  const int frow = lane & 15;

  f32x4 acc[2][4] = {};                 // [m-subtile][gate]

  if (isL0){
    if (t != 0){
      mm_merged(h0p_hi, h0p_lo, 256, P0hh, P0hh+256, 512, 256,
                m0, j0, wv, lane, rr, sw8, frow, acc, AsH, AsL, BsH, BsL);
    }
    mm_single64(Xp + (size_t)t*64, (size_t)TT*64, P0ih, 64,
                m0, j0, wv, lane, rr, sw8, frow, acc, AsH, BsH);
  } else {
    mm_merged(h0p_hi, h0p_lo, 256, P1ih, P1ih+256, 512, 256,
              m0, j0, wv, lane, rr, sw8, frow, acc, AsH, AsL, BsH, BsL);
    if (t != 1){
      mm_merged(h1p_hi, h1p_lo, 256, P1hh, P1hh+256, 512, 256,
                m0, j0, wv, lane, rr, sw8, frow, acc, AsH, AsL, BsH, BsL);
    }
  }

  // epilogue: lane holds all 4 gates. C map: col=lane&15, row=(lane>>4)*4+r
  const int j = j0 + frow;
  const float* bih = isL0 ? bih0 : bih1;
  const float* bhh = isL0 ? bhh0 : bhh1;
  float* cst = isL0 ? c0 : c1;
  __hip_bfloat16* ohi = isL0 ? h0o_hi : h1o_hi;
  __hip_bfloat16* olo = isL0 ? h0o_lo : h1o_lo;
  const int first = isL0 ? (t==0) : (t==1);
  const float b0 = bih[j]        + bhh[j];
  const float b1 = bih[HH + j]   + bhh[HH + j];
  const float b2 = bih[2*HH + j] + bhh[2*HH + j];
  const float b3 = bih[3*HH + j] + bhh[3*HH + j];
  #pragma unroll
  for (int mt=0; mt<2; ++mt){
    const int mrb = m0 + wv*32 + mt*16 + ((lane>>4)<<2);
    #pragma unroll
    for (int r=0; r<4; ++r){
      const size_t mi = (size_t)(mrb + r)*HH + j;
      float gi = acc[mt][0][r] + b0;
      float gf = acc[mt][1][r] + b1;
      float gg = acc[mt][2][r] + b2;
      float go = acc[mt][3][r] + b3;
      float cold = first ? 0.f : cst[mi];
      float cn = sigmoidf_(gf)*cold + sigmoidf_(gi)*tanhf(gg);
      float hv = sigmoidf_(go)*tanhf(cn);
      cst[mi] = cn;
      __hip_bfloat16 hb = __float2bfloat16(hv);
      ohi[mi] = hb;
      olo[mi] = __float2bfloat16(hv - __bfloat162float(hb));
    }
  }
}

// ---------------- fp32 tail (unchanged, proven) ----------------
__global__ __launch_bounds__(256) void gemm_nn(
    float* __restrict__ C, const float* __restrict__ A, const float* __restrict__ B,
    int K, int lda, int ldb, int ldc, int relu)
{
  __shared__ float As_[16][68];
  __shared__ float Bs_[16][64];
  float acc[4][4] = {};
  const int tx = threadIdx.x;
  const int m0 = blockIdx.y<<6, n0 = blockIdx.x<<6;
  const int am = tx>>2, ak = (tx&3)<<2;
  const int bk = tx>>4, bn = (tx&15)<<2;
  const int mm = (tx>>4)<<2, nc = (tx&15)<<2;
  for (int kb=0; kb<K; kb+=16){
    float4 av = *reinterpret_cast<const float4*>(A + (size_t)(m0+am)*lda + kb + ak);
    As_[ak][am]=av.x; As_[ak+1][am]=av.y; As_[ak+2][am]=av.z; As_[ak+3][am]=av.w;
    *reinterpret_cast<float4*>(&Bs_[bk][bn]) =
      *reinterpret_cast<const float4*>(B + (size_t)(kb+bk)*ldb + n0 + bn);
    __syncthreads();
    #pragma unroll
    for (int k=0;k<16;k++){
      float4 a4 = *reinterpret_cast<const float4*>(&As_[k][mm]);
      float4 b4 = *reinterpret_cast<const float4*>(&Bs_[k][nc]);
      acc[0][0]=fmaf(a4.x,b4.x,acc[0][0]); acc[0][1]=fmaf(a4.x,b4.y,acc[0][1]);
      acc[0][2]=fmaf(a4.x,b4.z,acc[0][2]); acc[0][3]=fmaf(a4.x,b4.w,acc[0][3]);
      acc[1][0]=fmaf(a4.y,b4.x,acc[1][0]); acc[1][1]=fmaf(a4.y,b4.y,acc[1][1]);
      acc[1][2]=fmaf(a4.y,b4.z,acc[1][2]); acc[1][3]=fmaf(a4.y,b4.w,acc[1][3]);
      acc[2][0]=fmaf(a4.z,b4.x,acc[2][0]); acc[2][1]=fmaf(a4.z,b4.y,acc[2][1]);
      acc[2][2]=fmaf(a4.z,b4.z,acc[2][2]); acc[2][3]=fmaf(a4.z,b4.w,acc[2][3]);
      acc[3][0]=fmaf(a4.w,b4.x,acc[3][0]); acc[3][1]=fmaf(a4.w,b4.y,acc[3][1]);
      acc[3][2]=fmaf(a4.w,b4.z,acc[3][2]); acc[3][3]=fmaf(a4.w,b4.w,acc[3][3]);
    }
    __syncthreads();
  }
  #pragma unroll
  for (int r=0;r<4;r++){
    float4 v = make_float4(acc[r][0],acc[r][1],acc[r][2],acc[r][3]);
    if (relu){ v.x=fmaxf(v.x,0.f); v.y=fmaxf(v.y,0.f); v.z=fmaxf(v.z,0.f); v.w=fmaxf(v.w,0.f); }
    *reinterpret_cast<float4*>(C + (size_t)(m0+mm+r)*ldc + n0 + nc) = v;
  }
}

__global__ __launch_bounds__(256) void gemm_nt(
    float* __restrict__ C, const float* __restrict__ A, const float* __restrict__ B,
    int K, int lda, int ldb, int ldc)
{
  __shared__ float As_[16][68];
  __shared__ float Bs_[16][68];
  float acc[4][4] = {};
  const int tx = threadIdx.x;
  const int m0 = blockIdx.y<<6, n0 = blockIdx.x<<6;
  const int am = tx>>2, ak = (tx&3)<<2;
  const int mm = (tx>>4)<<2, nc = (tx&15)<<2;
  for (int kb=0; kb<K; kb+=16){
    float4 av = *reinterpret_cast<const float4*>(A + (size_t)(m0+am)*lda + kb + ak);
    As_[ak][am]=av.x; As_[ak+1][am]=av.y; As_[ak+2][am]=av.z; As_[ak+3][am]=av.w;
    float4 bv = *reinterpret_cast<const float4*>(B + (size_t)(n0+am)*ldb + kb + ak);
    Bs_[ak][am]=bv.x; Bs_[ak+1][am]=bv.y; Bs_[ak+2][am]=bv.z; Bs_[ak+3][am]=bv.w;
    __syncthreads();
    #pragma unroll
    for (int k=0;k<16;k++){
      float4 a4 = *reinterpret_cast<const float4*>(&As_[k][mm]);
      float4 b4 = *reinterpret_cast<const float4*>(&Bs_[k][nc]);
      acc[0][0]=fmaf(a4.x,b4.x,acc[0][0]); acc[0][1]=fmaf(a4.x,b4.y,acc[0][1]);
      acc[0][2]=fmaf(a4.x,b4.z,acc[0][2]); acc[0][3]=fmaf(a4.x,b4.w,acc[0][3]);
      acc[1][0]=fmaf(a4.y,b4.x,acc[1][0]); acc[1][1]=fmaf(a4.y,b4.y,acc[1][1]);
      acc[1][2]=fmaf(a4.y,b4.z,acc[1][2]); acc[1][3]=fmaf(a4.y,b4.w,acc[1][3]);
      acc[2][0]=fmaf(a4.z,b4.x,acc[2][0]); acc[2][1]=fmaf(a4.z,b4.y,acc[2][1]);
      acc[2][2]=fmaf(a4.z,b4.z,acc[2][2]); acc[2][3]=fmaf(a4.z,b4.w,acc[2][3]);
      acc[3][0]=fmaf(a4.w,b4.x,acc[3][0]); acc[3][1]=fmaf(a4.w,b4.y,acc[3][1]);
      acc[3][2]=fmaf(a4.w,b4.z,acc[3][2]); acc[3][3]=fmaf(a4.w,b4.w,acc[3][3]);
    }
    __syncthreads();
  }
  #pragma unroll
  for (int r=0;r<4;r++){
    float4 v = make_float4(acc[r][0],acc[r][1],acc[r][2],acc[r][3]);
    *reinterpret_cast<float4*>(C + (size_t)(m0+mm+r)*ldc + n0 + nc) = v;
  }
}

__global__ __launch_bounds__(256) void rowstat(const float* __restrict__ nf,
    float* __restrict__ xc, float* __restrict__ dvec)
{
  __shared__ float red[256];
  int n = blockIdx.x, tx = threadIdx.x;
  float v = nf[(size_t)n*HH + tx];
  red[tx] = v; __syncthreads();
  for (int s=128; s>0; s>>=1){ if (tx<s) red[tx]+=red[tx+s]; __syncthreads(); }
  float mean = red[0] * (1.0f/HH);
  __syncthreads();
  float d = v - mean;
  xc[(size_t)n*HH + tx] = d;
  red[tx] = d*d; __syncthreads();
  for (int s=128; s>0; s>>=1){ if (tx<s) red[tx]+=red[tx+s]; __syncthreads(); }
  if (tx==0) dvec[n] = sqrtf(red[0]);
}

__global__ __launch_bounds__(256) void rowsum(const float* __restrict__ cov,
    const float* __restrict__ dvec, float* __restrict__ dinv)
{
  __shared__ float red[256];
  int i = blockIdx.x, tx = threadIdx.x;
  float di = dvec[i];
  float s = 0.f;
  for (int jj=tx; jj<NN; jj+=256){
    float r = cov[(size_t)i*NN + jj] / (di * dvec[jj]);
    if (r != r) r = 0.f; else r = fminf(1.f, fmaxf(-1.f, r));
    s += r;
  }
  red[tx]=s; __syncthreads();
  for (int st=128; st>0; st>>=1){ if (tx<st) red[tx]+=red[tx+st]; __syncthreads(); }
  if (tx==0){
    float tot = red[0] + 1.0f;
    float p = powf(tot, -0.5f);
    if (isinf(p)) p = 0.f;
    dinv[i] = p;
  }
}

__global__ __launch_bounds__(256) void adjnorm(float* __restrict__ cov,
    const float* __restrict__ dvec, const float* __restrict__ dinv)
{
  size_t idx = (size_t)blockIdx.x*256 + threadIdx.x;
  int i = (int)(idx >> 11), jj = (int)(idx & (NN-1));
  float r = cov[idx] / (dvec[i]*dvec[jj]);
  if (r != r) r = 0.f; else r = fminf(1.f, fmaxf(-1.f, r));
  if (i==jj) r += 1.f;
  cov[idx] = dinv[i]*r*dinv[jj];
}

__global__ __launch_bounds__(128) void predk(const float* __restrict__ G2,
    const float* __restrict__ Wfc, const float* __restrict__ bfc, float* __restrict__ out)
{
  int n = blockIdx.x, tx = threadIdx.x;
  float v = G2[(size_t)n*128 + tx] * Wfc[tx];
  for (int off=32; off>0; off>>=1) v += __shfl_down(v, off);
  __shared__ float p[2];
  if ((tx&63)==0) p[tx>>6] = v;
  __syncthreads();
  if (tx==0) out[n] = p[0] + p[1] + bfc[0];
}

extern "C" void kernel_launch(void* const* d_in, const int* in_sizes, int n_in,
                              void* d_out, int out_size, void* d_ws, size_t ws_size,
                              hipStream_t stream)
{
  const float* x    = (const float*)d_in[0];
  const float* Wih0 = (const float*)d_in[1];
  const float* Whh0 = (const float*)d_in[2];
  const float* bih0 = (const float*)d_in[3];
  const float* bhh0 = (const float*)d_in[4];
  const float* Wih1 = (const float*)d_in[5];
  const float* Whh1 = (const float*)d_in[6];
  const float* bih1 = (const float*)d_in[7];
  const float* bhh1 = (const float*)d_in[8];
  const float* Wg1  = (const float*)d_in[9];
  const float* Wg2  = (const float*)d_in[10];
  const float* Wfc  = (const float*)d_in[11];
  const float* bfc  = (const float*)d_in[12];
  float* out = (float*)d_out;

  char* w = (char*)d_ws;
  auto alloc = [&](size_t bytes){ char* p = w; w += (bytes + 255) & ~(size_t)255; return p; };
  __hip_bfloat16* Xp   = (__hip_bfloat16*)alloc((size_t)NN*TT*64*2);
  __hip_bfloat16* P0hh = (__hip_bfloat16*)alloc((size_t)1024*512*2);
  __hip_bfloat16* P1ih = (__hip_bfloat16*)alloc((size_t)1024*512*2);
  __hip_bfloat16* P1hh = (__hip_bfloat16*)alloc((size_t)1024*512*2);
  __hip_bfloat16* P0ih = (__hip_bfloat16*)alloc((size_t)1024*64*2);
  __hip_bfloat16 *H0hi[2], *H0lo[2], *H1hi[2], *H1lo[2];
  for (int i=0;i<2;i++){ H0hi[i]=(__hip_bfloat16*)alloc((size_t)NN*HH*2);
                         H0lo[i]=(__hip_bfloat16*)alloc((size_t)NN*HH*2); }
  for (int i=0;i<2;i++){ H1hi[i]=(__hip_bfloat16*)alloc((size_t)NN*HH*2);
                         H1lo[i]=(__hip_bfloat16*)alloc((size_t)NN*HH*2); }
  float* c0   = (float*)alloc((size_t)NN*HH*4);
  float* c1   = (float*)alloc((size_t)NN*HH*4);
  float* nf   = (float*)alloc((size_t)NN*HH*4);
  float* xc   = (float*)alloc((size_t)NN*HH*4);
  float* cov  = (float*)alloc((size_t)NN*NN*4);
  float* t1   = (float*)alloc((size_t)NN*HH*4);
  float* G1   = (float*)alloc((size_t)NN*HH*4);
  float* t2   = (float*)alloc((size_t)NN*128*4);
  float* G2   = (float*)alloc((size_t)NN*128*4);
  float* dvec = (float*)alloc((size_t)NN*4);
  float* dinv = (float*)alloc((size_t)NN*4);

  hipLaunchKernelGGL(pack_w2, dim3(1024), dim3(256), 0, stream, Whh0, P0hh);
  hipLaunchKernelGGL(pack_w2, dim3(1024), dim3(256), 0, stream, Wih1, P1ih);
  hipLaunchKernelGGL(pack_w2, dim3(1024), dim3(256), 0, stream, Whh1, P1hh);
  hipLaunchKernelGGL(pack_w0, dim3(64),   dim3(256), 0, stream, Wih0, P0ih);
  hipLaunchKernelGGL(pack_x,  dim3(2048), dim3(256), 0, stream, x, Xp);

  // skewed recurrence: launch t runs L0(t) and L1(t-1)
  for (int t=0; t<=TT; ++t){
    const __hip_bfloat16 *h0p_hi = H0hi[(t+1)&1], *h0p_lo = H0lo[(t+1)&1];
    __hip_bfloat16 *h0o_hi = H0hi[t&1], *h0o_lo = H0lo[t&1];
    const __hip_bfloat16 *h1p_hi = H1hi[t&1], *h1p_lo = H1lo[t&1];
    __hip_bfloat16 *h1o_hi = H1hi[(t+1)&1], *h1o_lo = H1lo[(t+1)&1];
    hipLaunchKernelGGL(lstm2_step, dim3(512), dim3(256), 0, stream,
        t, Xp, P0ih, P0hh, P1ih, P1hh, bih0, bhh0, bih1, bhh1,
        h0p_hi, h0p_lo, h0o_hi, h0o_lo, h1p_hi, h1p_lo, h1o_hi, h1o_lo, c0, c1);
  }
  // final h1 (step 255, written at launch t=256) lives in H1[1]
  hipLaunchKernelGGL(recon_nf, dim3(2048), dim3(256), 0, stream, H1hi[1], H1lo[1], nf);

  hipLaunchKernelGGL(rowstat, dim3(NN), dim3(256), 0, stream, nf, xc, dvec);
  hipLaunchKernelGGL(gemm_nt, dim3(NN/64, NN/64), dim3(256), 0, stream,
      cov, xc, xc, HH, HH, HH, NN);
  hipLaunchKernelGGL(rowsum, dim3(NN), dim3(256), 0, stream, cov, dvec, dinv);
  hipLaunchKernelGGL(adjnorm, dim3(NN*NN/256), dim3(256), 0, stream, cov, dvec, dinv);

  hipLaunchKernelGGL(gemm_nn, dim3(HH/64, NN/64), dim3(256), 0, stream,
      t1, nf, Wg1, HH, HH, HH, HH, 0);
  hipLaunchKernelGGL(gemm_nn, dim3(HH/64, NN/64), dim3(256), 0, stream,
      G1, cov, t1, NN, NN, HH, HH, 1);
  hipLaunchKernelGGL(gemm_nn, dim3(128/64, NN/64), dim3(256), 0, stream,
      t2, G1, Wg2, HH, HH, 128, 128, 0);
  hipLaunchKernelGGL(gemm_nn, dim3(128/64, NN/64), dim3(256), 0, stream,
      G2, cov, t2, NN, NN, 128, 128, 0);
  hipLaunchKernelGGL(predk, dim3(NN), dim3(128), 0, stream, G2, Wfc, bfc, out);
}